// Round 6
// baseline (12723.935 us; speedup 1.0000x reference)
//
#include <hip/hip_runtime.h>
#include <cstdint>

// ---- problem dims ----
#define Hdim 512
#define Bdim 128
#define Tdim 512
#define FUT  32
#define TT   (Tdim + FUT)   // 544
#define RD   8              // h ring depth (parity & 7)
#define FSTR 32             // flag stride in u32 (one flag per 128-B line)
#define CAPIT (1 << 22)     // spin-loop safety cap (fail fast instead of hang)

typedef _Float16 f16;
typedef f16      half8  __attribute__((ext_vector_type(8)));
typedef float    f32x4  __attribute__((ext_vector_type(4)));
typedef unsigned long long ull;

// ---- ws layout (float offsets) ----
#define AW1_OFF  0
#define AW2R_OFF (AW1_OFF + 1048576)     // W_hh2 packed (critical gemm, LDS-resident)
#define AW2I_OFF (AW2R_OFF + 1048576)    // W_ih2 packed (shadow gemm, L2-cached plain loads)
#define B1P_OFF  (AW2I_OFF + 1048576)
#define B2P_OFF  (B1P_OFF + 2048)
#define WX1_OFF  (B2P_OFF + 2048)
#define XT_OFF   (WX1_OFF + 2048)        // [512 t][128 b] f32
#define H1G_OFF  (XT_OFF + 65536)        // h1 ring: 8 par x 2 spl x 65536 f16
#define H2G_OFF  (H1G_OFF + 524288)      // h2 ring
#define ARR_OFF  (H2G_OFF + 524288)      // flags + per-XCD counters (8192 u32 = 256 lines)
#define WS_FLOATS (ARR_OFF + 8192)

// flag lines: f1 @ g*32+i (0..63), f2 @ 128+g*32+i, fog @ 192+g*4+q,
// XCD counters @ 200+xcd.  All agent-scope atomics (R0/R4/R5-proven).
#define F1Gp(g,i)  (flg + ((g)*32 + (i)) * FSTR)
#define F2Gp(g,i)  (flg + (128 + (g)*32 + (i)) * FSTR)
#define FOGp(g,q)  (flg + (192 + (g)*4 + (q)) * FSTR)

__device__ __forceinline__ float sigm(float v) { return 1.0f / (1.0f + __expf(-v)); }
__device__ __forceinline__ float tanh_fast(float v) {
    v = fminf(fmaxf(v, -20.0f), 20.0f);
    float e = __expf(2.0f * v);
    return (e - 1.0f) / (e + 1.0f);
}

// ---- proven coherent primitives: relaxed agent-scope atomics only ----
__device__ __forceinline__ unsigned cohloadu(const unsigned* p) {
    return __hip_atomic_load(p, __ATOMIC_RELAXED, __HIP_MEMORY_SCOPE_AGENT);
}
__device__ __forceinline__ void cohstoreu(unsigned* p, unsigned v) {
    __hip_atomic_store(p, v, __ATOMIC_RELAXED, __HIP_MEMORY_SCOPE_AGENT);
}
__device__ __forceinline__ ull cohload64(const ull* p) {
    return __hip_atomic_load(p, __ATOMIC_RELAXED, __HIP_MEMORY_SCOPE_AGENT);
}
__device__ __forceinline__ void cohstore64(ull* p, ull v) {
    __hip_atomic_store(p, v, __ATOMIC_RELAXED, __HIP_MEMORY_SCOPE_AGENT);
}
union HB  { ull u[2]; half8 h; };
__device__ __forceinline__ half8 fragload(const half8* p) {
    const ull* q = (const ull*)p;
    HB t; t.u[0] = cohload64(q); t.u[1] = cohload64(q + 1);
    return t.h;
}

// ---------- prep ----------
__global__ void lstm_prep(const float* __restrict__ x,
                          const float* __restrict__ W_ih1, const float* __restrict__ W_hh1,
                          const float* __restrict__ b_ih1, const float* __restrict__ b_hh1,
                          const float* __restrict__ W_ih2, const float* __restrict__ W_hh2,
                          const float* __restrict__ b_ih2, const float* __restrict__ b_hh2,
                          float* __restrict__ ws, float* __restrict__ out) {
    int i = blockIdx.x * blockDim.x + threadIdx.x;
    f16* aw1  = (f16*)(ws + AW1_OFF);
    f16* aw2r = (f16*)(ws + AW2R_OFF);
    f16* aw2i = (f16*)(ws + AW2I_OFF);

    if (i < 131072) {                         // AW1 <- W_hh1 (proven packing)
        int mt = i >> 10, rest = i & 1023, ks = rest >> 6, lane = rest & 63;
        int m = mt * 16 + (lane & 15);
        int u = m >> 2, g = m & 3;
        int kbase = ks * 32 + (lane >> 4) * 8;
        size_t ohi = ((((size_t)mt * 16 + ks) * 2 + 0) * 64 + lane) * 8;
        size_t olo = ((((size_t)mt * 16 + ks) * 2 + 1) * 64 + lane) * 8;
        #pragma unroll
        for (int j = 0; j < 8; ++j) {
            float wv = W_hh1[(size_t)(g * Hdim + u) * Hdim + kbase + j];
            f16 hi = (f16)wv;
            f16 lo = (f16)(wv - (float)hi);
            aw1[ohi + j] = hi; aw1[olo + j] = lo;
        }
    }
    if (i >= 131072 && i < 262144) {          // AW2R <- W_hh2 (same format)
        int i2 = i - 131072;
        int mt = i2 >> 10, rest = i2 & 1023, ks = rest >> 6, lane = rest & 63;
        int m = mt * 16 + (lane & 15);
        int u = m >> 2, g = m & 3;
        int kbase = ks * 32 + (lane >> 4) * 8;
        size_t ohi = ((((size_t)mt * 16 + ks) * 2 + 0) * 64 + lane) * 8;
        size_t olo = ((((size_t)mt * 16 + ks) * 2 + 1) * 64 + lane) * 8;
        #pragma unroll
        for (int j = 0; j < 8; ++j) {
            float wv = W_hh2[(size_t)(g * Hdim + u) * Hdim + kbase + j];
            f16 hi = (f16)wv;
            f16 lo = (f16)(wv - (float)hi);
            aw2r[ohi + j] = hi; aw2r[olo + j] = lo;
        }
    }
    if (i >= 262144 && i < 393216) {          // AW2I <- W_ih2 (same format)
        int i2 = i - 262144;
        int mt = i2 >> 10, rest = i2 & 1023, ks = rest >> 6, lane = rest & 63;
        int m = mt * 16 + (lane & 15);
        int u = m >> 2, g = m & 3;
        int kbase = ks * 32 + (lane >> 4) * 8;
        size_t ohi = ((((size_t)mt * 16 + ks) * 2 + 0) * 64 + lane) * 8;
        size_t olo = ((((size_t)mt * 16 + ks) * 2 + 1) * 64 + lane) * 8;
        #pragma unroll
        for (int j = 0; j < 8; ++j) {
            float wv = W_ih2[(size_t)(g * Hdim + u) * Hdim + kbase + j];
            f16 hi = (f16)wv;
            f16 lo = (f16)(wv - (float)hi);
            aw2i[ohi + j] = hi; aw2i[olo + j] = lo;
        }
    }
    if (i < Hdim) {
        float4 bb1 = { b_ih1[i] + b_hh1[i],               b_ih1[Hdim+i] + b_hh1[Hdim+i],
                       b_ih1[2*Hdim+i] + b_hh1[2*Hdim+i], b_ih1[3*Hdim+i] + b_hh1[3*Hdim+i] };
        float4 bb2 = { b_ih2[i] + b_hh2[i],               b_ih2[Hdim+i] + b_hh2[Hdim+i],
                       b_ih2[2*Hdim+i] + b_hh2[2*Hdim+i], b_ih2[3*Hdim+i] + b_hh2[3*Hdim+i] };
        float4 wx  = { W_ih1[i], W_ih1[Hdim+i], W_ih1[2*Hdim+i], W_ih1[3*Hdim+i] };
        ((float4*)(ws + B1P_OFF))[i] = bb1;
        ((float4*)(ws + B2P_OFF))[i] = bb2;
        ((float4*)(ws + WX1_OFF))[i] = wx;
    }
    if (i < Tdim * Bdim) {
        int t = i >> 7, b = i & 127;
        ws[XT_OFF + i] = x[b * Tdim + t];
    }
    if (i < 262144) {                          // zero h1/h2 rings
        ((ull*)(ws + H1G_OFF))[i] = 0;
        ((ull*)(ws + H2G_OFF))[i] = 0;
    }
    if (i < 8192) ((unsigned*)(ws + ARR_OFF))[i] = 0u;
    if (i < Bdim * TT) out[i] = 0.f;           // out is accumulated via atomicAdd
}

// ---------- persistent main kernel: 3-stage XCD-partitioned pipeline ----------
// Roles by measured XCC_ID (placement-safe), ALL shared data via agent atomics:
//   XCD0/1: L1 group 0/1 (32 blk, 16 units, K=512 h1 recurrence)
//   XCD2/3: L2 group 0/1 (32 blk, 16 units): critical W_hh2 gemm on h2 ring;
//           P(s+1)=W_ih2.h1(s+1)+b2 computed IN THE WAIT SHADOW, kept in regs
//           (W_ih2 via plain loads -> XCD-L2-cached; no P ring, no L2in stage)
//   XCD4:   8 out blocks (4 per group, ks-quartered, atomicAdd into out)
__global__ __launch_bounds__(256, 1) void lstm_main(float* ws,
                                                    const float* __restrict__ Wout,
                                                    const float* __restrict__ bout,
                                                    float* __restrict__ out) {
    const int tid  = threadIdx.x;
    const int w    = tid >> 6;
    const int lane = tid & 63;
    const int quad = lane >> 4;
    const int col  = lane & 15;

    __shared__ f16   awlds[65536];       // 128 KB weight A-fragments (forces 1 blk/CU)
    __shared__ float wout_lds[Hdim];
    __shared__ float psum[4][64];
    __shared__ float xflds[64];
    __shared__ float qpart[4][64];
    __shared__ __align__(16) ull hstg[512];
    __shared__ int sXcd, sOrd, badf;

    unsigned* flg = (unsigned*)(ws + ARR_OFF);
    unsigned short* stg = (unsigned short*)hstg;
    const float* xT = ws + XT_OFF;
    const float bout0 = bout[0];

    // ---- runtime XCD discovery + per-XCD ordinal ----
    if (tid == 0) {
        badf = 0;
        unsigned xcc;
        asm volatile("s_getreg_b32 %0, hwreg(HW_REG_XCC_ID, 0, 32)" : "=s"(xcc));
        xcc &= 0xF;
        sXcd = (int)xcc;
        sOrd = (int)atomicAdd(flg + (200 + xcc) * FSTR, 1u);
    }
    __syncthreads();
    const int xcd = sXcd, ord = sOrd;

    const bool is1   = (xcd < 2);
    const bool is2   = (xcd == 2 || xcd == 3);
    const bool isout = (xcd == 4) && (ord < 8);
    const bool active = ((is1 || is2) && ord < 32) || isout;
    if (!active) return;

    const int gA  = is1 ? xcd : is2 ? (xcd - 2) : (ord >> 2);
    const int oq  = isout ? (ord & 3) : 0;
    const int ntw = gA * 4 + w;
    const int ks1 = ord >> 1, qp0 = (ord & 1) * 2;

    // ---- ring fragment planes (half8 index = (nt*16+ks)*64 + lane) ----
    auto h1pf = [&](int par, int spl) {
        return (const half8*)((const unsigned short*)(ws + H1G_OFF) + (size_t)(par*2+spl) * 65536); };
    auto h2pf = [&](int par, int spl) {
        return (const half8*)((const unsigned short*)(ws + H2G_OFF) + (size_t)(par*2+spl) * 65536); };
    auto h1ull = [&](int par, int spl) {
        return (ull*)(ws + H1G_OFF) + (size_t)(par*2+spl) * 16384; };
    auto h2ull = [&](int par, int spl) {
        return (ull*)(ws + H2G_OFF) + (size_t)(par*2+spl) * 16384; };

    // ---- one-time: weight slice -> LDS (L1: W_hh1, L2: W_hh2) ----
    if (is1 || is2) {
        const half8* s = (const half8*)(ws + (is1 ? AW1_OFF : AW2R_OFF)) + (size_t)ord * 8192;
        half8* d = (half8*)awlds;
        for (int i = tid; i < 8192; i += 256) d[i] = s[i];
    }
    wout_lds[tid]       = Wout[tid];
    wout_lds[256 + tid] = Wout[256 + tid];
    __syncthreads();

    // ---- shared GEMM core: 16 units x 64 cols, K=512 hi/lo, A from LDS ----
    auto gemm = [&](const half8* fh, const half8* fl, f32x4* acc) {
        half8 rh[16], rl[16];
        #pragma unroll
        for (int ks = 0; ks < 16; ++ks) {
            rh[ks] = fragload(fh + (ntw * 16 + ks) * 64 + lane);
            rl[ks] = fragload(fl + (ntw * 16 + ks) * 64 + lane);
        }
        const half8* aw8 = (const half8*)awlds;
        #pragma unroll
        for (int ks = 0; ks < 16; ++ks) {
            #pragma unroll
            for (int mt = 0; mt < 4; ++mt) {
                half8 ah = aw8[((mt * 16 + ks) * 2 + 0) * 64 + lane];
                half8 al = aw8[((mt * 16 + ks) * 2 + 1) * 64 + lane];
                acc[mt] = __builtin_amdgcn_mfma_f32_16x16x32_f16(ah, rh[ks], acc[mt], 0, 0, 0);
                acc[mt] = __builtin_amdgcn_mfma_f32_16x16x32_f16(al, rh[ks], acc[mt], 0, 0, 0);
                acc[mt] = __builtin_amdgcn_mfma_f32_16x16x32_f16(ah, rl[ks], acc[mt], 0, 0, 0);
            }
        }
    };

    // ---- staging + publish (agent-scope b64 stores, proven path) ----
    auto stage1 = [&](int mt, float hv) {
        f16 hhi = (f16)hv;
        f16 hlo = (f16)(hv - (float)hhi);
        int mq = mt * 4 + quad, qp = mq >> 3, jj = mq & 7;
        int hi = ((w * 2 + qp) * 16 + col) * 8 + jj;
        stg[hi]        = __builtin_bit_cast(unsigned short, hhi);
        stg[1024 + hi] = __builtin_bit_cast(unsigned short, hlo);
    };
    auto publish = [&](int dpar, bool to1) {
        __syncthreads();
        int f = 2 * tid;
        int spl = f >> 8, rmix = f & 255, ntl = rmix >> 6, rr = rmix & 63;
        int qp = rr >> 5, colp = (rr & 31) >> 1;
        size_t e = (((size_t)(gA * 4 + ntl) * 16 + ks1) * 64 + (qp0 + qp) * 16 + colp) * 2;
        ull* base = (to1 ? h1ull(dpar, spl) : h2ull(dpar, spl)) + e;
        cohstore64(base,     hstg[f]);
        cohstore64(base + 1, hstg[f + 1]);
    };

    // ================= LAYER 1 (h1 recurrence) =================
    if (is1) {
        const int bcol = ntw * 16 + col;
        float4 b1v[4], wxv[4]; float c1s[4];
        #pragma unroll
        for (int mt = 0; mt < 4; ++mt) {
            int u = ord * 16 + mt * 4 + quad;
            b1v[mt] = ((const float4*)(ws + B1P_OFF))[u];
            wxv[mt] = ((const float4*)(ws + WX1_OFF))[u];
            c1s[mt] = 0.f;
        }
        unsigned* myF1 = F1Gp(gA, ord);
        unsigned f2c = (tid < 64 && lane >= 32) ? 0u : 0xFFFFFFFFu;  // cached f2 (backpressure)

        auto wait_main = [&](unsigned T1, unsigned T2) {
            if (tid < 64 && !badf) {
                int gd = 0;
                for (;;) {
                    unsigned a = (lane < 32) ? cohloadu(F1Gp(gA, lane)) : 0xFFFFFFFFu;
                    if (lane >= 32 && f2c < T2) f2c = cohloadu(F2Gp(gA, lane - 32));
                    if (__all(a >= T1 && f2c >= T2)) break;
                    if (++gd > CAPIT) { badf = 1; break; }
                    __builtin_amdgcn_s_sleep(1);
                }
            }
            asm volatile("" ::: "memory");
            __syncthreads();
        };
        auto wait_fut = [&](unsigned T) {
            if (tid < 64 && !badf) {
                int gd = 0;
                for (;;) {
                    unsigned a = (lane < 32) ? cohloadu(F1Gp(gA, lane))
                                             : cohloadu(F2Gp(gA, lane - 32));
                    if (__all(a >= T)) break;
                    if (++gd > CAPIT) { badf = 1; break; }
                    __builtin_amdgcn_s_sleep(2);
                }
            }
            asm volatile("" ::: "memory");
            __syncthreads();
        };
        auto post1 = [&](unsigned v) {
            __syncthreads();               // tracked atomic stores drain before barrier
            if (tid == 0) cohstoreu(myF1, v);
        };
        auto l1_step = [&](int spar, int dpar, float xv) {
            f32x4 acc[4] = {};
            gemm(h1pf(spar, 0), h1pf(spar, 1), acc);
            #pragma unroll
            for (int mt = 0; mt < 4; ++mt) {
                f32x4 g = acc[mt];
                float pi = g[0] + b1v[mt].x + wxv[mt].x * xv;
                float pf = g[1] + b1v[mt].y + wxv[mt].y * xv;
                float pg = g[2] + b1v[mt].z + wxv[mt].z * xv;
                float po = g[3] + b1v[mt].w + wxv[mt].w * xv;
                float c = fmaf(sigm(pf), c1s[mt], sigm(pi) * tanh_fast(pg));
                c1s[mt] = c;
                stage1(mt, sigm(po) * tanh_fast(c));
            }
            publish(dpar, true);
        };

        // prologue: h1(0) from x(0), h1(-1)=0
        {
            float xv = xT[bcol];
            #pragma unroll
            for (int mt = 0; mt < 4; ++mt) {
                float pi = b1v[mt].x + wxv[mt].x * xv;
                float pg = b1v[mt].z + wxv[mt].z * xv;
                float po = b1v[mt].w + wxv[mt].w * xv;
                float c = sigm(pi) * tanh_fast(pg);
                c1s[mt] = c;
                stage1(mt, sigm(po) * tanh_fast(c));
            }
            publish(0, true);
            post1(1u);
        }
        // main: step t computes h1(t+1); f2>=t-6 guarantees L2's h1(t-7) reads done
        for (int t = 0; t <= Tdim - 2; ++t) {
            wait_main((unsigned)(t + 1), (t >= 7) ? (unsigned)(t - 6) : 0u);
            l1_step(t & 7, (t + 1) & 7, xT[(t + 1) * Bdim + bcol]);
            post1((unsigned)(t + 2));
        }
        // future: compute O(t-1) from h2 ring, feed back as x
        for (int t = Tdim; t < TT; ++t) {
            wait_fut((unsigned)t);
            {
                int bl = tid & 63, kh = tid >> 6;
                int nt2 = gA * 4 + (bl >> 4), nl = bl & 15;
                const half8* ph = h2pf((t - 1) & 7, 0);
                const half8* pl = h2pf((t - 1) & 7, 1);
                float a = 0.f;
                #pragma unroll
                for (int kk = 0; kk < 4; ++kk) {
                    int ks = kh * 4 + kk;
                    #pragma unroll
                    for (int qd = 0; qd < 4; ++qd) {
                        half8 vh = fragload(ph + (nt2 * 16 + ks) * 64 + qd * 16 + nl);
                        half8 vl = fragload(pl + (nt2 * 16 + ks) * 64 + qd * 16 + nl);
                        int ub = ks * 32 + qd * 8;
                        #pragma unroll
                        for (int j = 0; j < 8; ++j)
                            a = fmaf((float)vh[j] + (float)vl[j], wout_lds[ub + j], a);
                    }
                }
                psum[kh][bl] = a;
                __syncthreads();
                if (tid < 64)
                    xflds[tid] = psum[0][tid] + psum[1][tid] + psum[2][tid]
                               + psum[3][tid] + bout0;
                __syncthreads();
            }
            l1_step((t - 1) & 7, t & 7, xflds[bcol & 63]);
            post1((unsigned)(t + 1));
        }
    }
    // ================= LAYER 2: critical hh2 gemm + shadow P gemm =================
    else if (is2) {
        float c2s[4] = {0.f, 0.f, 0.f, 0.f};
        float4 b2v[4];
        #pragma unroll
        for (int mt = 0; mt < 4; ++mt)
            b2v[mt] = ((const float4*)(ws + B2P_OFF))[ord * 16 + mt * 4 + quad];
        unsigned* myF2 = F2Gp(gA, ord);
        const half8* wi = (const half8*)(ws + AW2I_OFF) + (size_t)ord * 8192;  // plain loads
        unsigned f1c  = (tid < 64 && lane < 32) ? 0u : 0xFFFFFFFFu;            // cached f1
        unsigned fogc = (tid < 64 && lane >= 32 && lane < 36) ? 0u : 0xFFFFFFFFu;

        auto waitF1 = [&](unsigned T) {      // shadow-phase wait (pre-satisfied usually)
            if (tid < 64 && !badf) {
                int gd = 0;
                for (;;) {
                    if (lane < 32 && f1c < T) f1c = cohloadu(F1Gp(gA, lane));
                    if (__all(f1c >= T)) break;
                    if (++gd > CAPIT) { badf = 1; break; }
                    __builtin_amdgcn_s_sleep(1);
                }
            }
            asm volatile("" ::: "memory");
            __syncthreads();
        };
        auto waitB = [&](unsigned T2, unsigned To) {   // critical wait: peers' h2 + fog
            if (tid < 64 && !badf) {
                int gd = 0;
                for (;;) {
                    unsigned a = (lane < 32) ? cohloadu(F2Gp(gA, lane)) : 0xFFFFFFFFu;
                    if (lane >= 32 && lane < 36 && fogc < To) fogc = cohloadu(FOGp(gA, lane - 32));
                    if (__all(a >= T2 && fogc >= To)) break;
                    if (++gd > CAPIT) { badf = 1; break; }
                    __builtin_amdgcn_s_sleep(1);
                }
            }
            asm volatile("" ::: "memory");
            __syncthreads();
        };

        // shadow gemm: accP += W_ih2 . h1(spar)  (A from L2-cached plain loads)
        f32x4 accP[4];
        auto gemmP = [&](int spar) {
            half8 rh[16], rl[16];
            const half8* fh = h1pf(spar, 0);
            const half8* fl = h1pf(spar, 1);
            #pragma unroll
            for (int ks = 0; ks < 16; ++ks) {
                rh[ks] = fragload(fh + (ntw * 16 + ks) * 64 + lane);
                rl[ks] = fragload(fl + (ntw * 16 + ks) * 64 + lane);
            }
            #pragma unroll
            for (int ks = 0; ks < 16; ++ks) {
                #pragma unroll
                for (int mt = 0; mt < 4; ++mt) {
                    half8 ah = wi[((mt * 16 + ks) * 2 + 0) * 64 + lane];
                    half8 al = wi[((mt * 16 + ks) * 2 + 1) * 64 + lane];
                    accP[mt] = __builtin_amdgcn_mfma_f32_16x16x32_f16(ah, rh[ks], accP[mt], 0, 0, 0);
                    accP[mt] = __builtin_amdgcn_mfma_f32_16x16x32_f16(al, rh[ks], accP[mt], 0, 0, 0);
                    accP[mt] = __builtin_amdgcn_mfma_f32_16x16x32_f16(ah, rl[ks], accP[mt], 0, 0, 0);
                }
            }
        };

        // prologue: P(0) from h1(0)
        waitF1(1u);
        #pragma unroll
        for (int mt = 0; mt < 4; ++mt)
            accP[mt] = (f32x4){b2v[mt].x, b2v[mt].y, b2v[mt].z, b2v[mt].w};
        gemmP(0);

        for (int s = 0; s < TT; ++s) {
            waitB((unsigned)s, (s >= 8) ? (unsigned)(s - 7) : 0u);
            f32x4 acc[4] = {};
            if (s > 0) gemm(h2pf((s - 1) & 7, 0), h2pf((s - 1) & 7, 1), acc);  // h2(-1)=0
            #pragma unroll
            for (int mt = 0; mt < 4; ++mt) {
                f32x4 g = acc[mt];
                f32x4 p = accP[mt];
                float pi = g[0] + p[0], pf = g[1] + p[1];
                float pg = g[2] + p[2], po = g[3] + p[3];
                float c = fmaf(sigm(pf), c2s[mt], sigm(pi) * tanh_fast(pg));
                c2s[mt] = c;
                stage1(mt, sigm(po) * tanh_fast(c));
            }
            publish(s & 7, false);
            __syncthreads();
            if (tid == 0) cohstoreu(myF2, (unsigned)(s + 1));
            if (s + 1 < TT) {                 // shadow: P(s+1) in the f2-wait shadow
                waitF1((unsigned)(s + 2));
                #pragma unroll
                for (int mt = 0; mt < 4; ++mt)
                    accP[mt] = (f32x4){b2v[mt].x, b2v[mt].y, b2v[mt].z, b2v[mt].w};
                gemmP((s + 1) & 7);
            }
        }
    }
    // ================= OUT blocks (4 per group, ks-quartered, atomicAdd) =================
    else {
        int b = gA * 64 + lane;
        int nt = b >> 4, nl = b & 15;
        int ks = oq * 4 + w;                 // one ks per wave
        unsigned* myFO = FOGp(gA, oq);

        auto waitO = [&](unsigned T) {
            if (tid < 64 && !badf) {
                int gd = 0;
                for (;;) {
                    unsigned a = (lane < 32) ? cohloadu(F2Gp(gA, lane)) : 0xFFFFFFFFu;
                    if (__all(a >= T)) break;
                    if (++gd > CAPIT) { badf = 1; break; }
                    __builtin_amdgcn_s_sleep(2);
                }
            }
            asm volatile("" ::: "memory");
            __syncthreads();
        };

        for (int s = 0; s < TT; ++s) {
            waitO((unsigned)(s + 1));
            const half8* ph = h2pf(s & 7, 0);
            const half8* pl = h2pf(s & 7, 1);
            float a = 0.f;
            #pragma unroll
            for (int qd = 0; qd < 4; ++qd) {
                half8 vh = fragload(ph + (nt * 16 + ks) * 64 + qd * 16 + nl);
                half8 vl = fragload(pl + (nt * 16 + ks) * 64 + qd * 16 + nl);
                int ub = ks * 32 + qd * 8;
                #pragma unroll
                for (int j = 0; j < 8; ++j)
                    a = fmaf((float)vh[j] + (float)vl[j], wout_lds[ub + j], a);
            }
            qpart[w][lane] = a;
            __syncthreads();
            if (w == 0) {
                float v = qpart[0][lane] + qpart[1][lane] + qpart[2][lane] + qpart[3][lane];
                if (oq == 0) v += bout0;
                atomicAdd(&out[(size_t)b * TT + s], v);
            }
            __syncthreads();
            if (tid == 0) cohstoreu(myFO, (unsigned)(s + 1));
        }
    }
}

extern "C" void kernel_launch(void* const* d_in, const int* in_sizes, int n_in,
                              void* d_out, int out_size, void* d_ws, size_t ws_size,
                              hipStream_t stream) {
    const float* x     = (const float*)d_in[0];
    const float* W_ih1 = (const float*)d_in[1];
    const float* W_hh1 = (const float*)d_in[2];
    const float* b_ih1 = (const float*)d_in[3];
    const float* b_hh1 = (const float*)d_in[4];
    const float* W_ih2 = (const float*)d_in[5];
    const float* W_hh2 = (const float*)d_in[6];
    const float* b_ih2 = (const float*)d_in[7];
    const float* b_hh2 = (const float*)d_in[8];
    const float* W_out = (const float*)d_in[9];
    const float* b_out = (const float*)d_in[10];
    float* ws  = (float*)d_ws;
    float* out = (float*)d_out;

    hipLaunchKernelGGL(lstm_prep, dim3(1536), dim3(256), 0, stream,
                       x, W_ih1, W_hh1, b_ih1, b_hh1, W_ih2, W_hh2, b_ih2, b_hh2, ws, out);
    hipLaunchKernelGGL(lstm_main, dim3(256), dim3(256), 0, stream,
                       ws, W_out, b_out, out);
}

// Round 10
// 3886.565 us; speedup vs baseline: 3.2738x; 3.2738x over previous
//
#include <hip/hip_runtime.h>
#include <cstdint>

// ---- problem dims ----
#define Hdim 512
#define Bdim 128
#define Tdim 512
#define FUT  32
#define TT   (Tdim + FUT)   // 544
// Two independent batch-groups (A: cols 0-63 / nt 0-3, B: cols 64-127 / nt 4-7).
// All recurrences (h1, h2, out-feedback) are closed within a group.
#define NB1  64             // layer-1 blocks: 2 groups x 32 (16 units, 1 nt/wave)
#define NB2  128            // layer-2 blocks: 2 groups x 64 (8 units, 1 nt/wave)
#define NBO  2              // out blocks: 1 per group
#define NBLK (NB1 + NB2 + NBO)   // 194
#define RD   8              // h ring depth (parity & 7)
#define FSTR 32             // flag stride in u32 (one flag per 128-B line)
// flag line bases: f1 @ g*32 + i (lines 0..63), f2 @ 64 + g*64 + i (64..191), fo @ 200+g
#define F2B  64
#define FOB  200

typedef _Float16 f16;
typedef f16   half8 __attribute__((ext_vector_type(8)));
typedef float f32x4 __attribute__((ext_vector_type(4)));
typedef unsigned long long ull;

// ---- ws layout (float offsets) ----
#define AW1_OFF 0
#define AW2_OFF (AW1_OFF + 1048576)
#define B1P_OFF (AW2_OFF + 2097152)
#define B2P_OFF (B1P_OFF + 2048)
#define WX1_OFF (B2P_OFF + 2048)
#define XT_OFF  (WX1_OFF + 2048)      // [512 t][128 b] f32
#define H1P_OFF (XT_OFF + 65536)      // 8 par x 2 spl x 65536 f16 = 524288 floats
#define H2P_OFF (H1P_OFF + 524288)
#define ARR_OFF (H2P_OFF + 524288)    // padded flags (8192 u32 = 256 lines)
#define WS_FLOATS (ARR_OFF + 8192)

__device__ __forceinline__ float sigm(float v) { return 1.0f / (1.0f + __expf(-v)); }
__device__ __forceinline__ float tanh_fast(float v) {
    v = fminf(fmaxf(v, -20.0f), 20.0f);
    float e = __expf(2.0f * v);
    return (e - 1.0f) / (e + 1.0f);
}

__device__ __forceinline__ unsigned cohloadu(const unsigned* p) {
    return __hip_atomic_load(p, __ATOMIC_RELAXED, __HIP_MEMORY_SCOPE_AGENT);
}
__device__ __forceinline__ ull cohload64(const ull* p) {
    return __hip_atomic_load(p, __ATOMIC_RELAXED, __HIP_MEMORY_SCOPE_AGENT);
}
__device__ __forceinline__ void cohstore64(ull* p, ull v) {
    __hip_atomic_store(p, v, __ATOMIC_RELAXED, __HIP_MEMORY_SCOPE_AGENT);
}

union HB { ull u[2]; half8 h; };
// LLC-direct 16-B fragment load: TWO relaxed agent b64 atomics (R11/R13-proven,
// stays schedulable; R12's volatile variant serialized issue -> 2.4x regression).
__device__ __forceinline__ half8 fragload(const half8* p) {
    const ull* q = (const ull*)p;
    HB t; t.u[0] = cohload64(q); t.u[1] = cohload64(q + 1);
    return t.h;
}

// ---------- prep (layouts unchanged) ----------
__global__ void lstm_prep(const float* __restrict__ x,
                          const float* __restrict__ W_ih1, const float* __restrict__ W_hh1,
                          const float* __restrict__ b_ih1, const float* __restrict__ b_hh1,
                          const float* __restrict__ W_ih2, const float* __restrict__ W_hh2,
                          const float* __restrict__ b_ih2, const float* __restrict__ b_hh2,
                          float* __restrict__ ws) {
    int i = blockIdx.x * blockDim.x + threadIdx.x;
    f16* aw1 = (f16*)(ws + AW1_OFF);
    f16* aw2 = (f16*)(ws + AW2_OFF);

    if (i < 131072) {                         // AW1
        int mt = i >> 10, rest = i & 1023, ks = rest >> 6, lane = rest & 63;
        int m = mt * 16 + (lane & 15);
        int u = m >> 2, g = m & 3;
        int kbase = ks * 32 + (lane >> 4) * 8;
        size_t ohi = ((((size_t)mt * 16 + ks) * 2 + 0) * 64 + lane) * 8;
        size_t olo = ((((size_t)mt * 16 + ks) * 2 + 1) * 64 + lane) * 8;
        #pragma unroll
        for (int j = 0; j < 8; ++j) {
            float wv = W_hh1[(size_t)(g * Hdim + u) * Hdim + kbase + j];
            f16 hi = (f16)wv;
            f16 lo = (f16)(wv - (float)hi);
            aw1[ohi + j] = hi; aw1[olo + j] = lo;
        }
    }
    if (i >= 131072 && i < 393216) {          // AW2 (K=1024 concat)
        int i2 = i - 131072;
        int mt = i2 >> 11, rest = i2 & 2047, ks = rest >> 6, lane = rest & 63;
        int m = mt * 16 + (lane & 15);
        int u = m >> 2, g = m & 3;
        int kbase = ks * 32 + (lane >> 4) * 8;
        size_t ohi = ((((size_t)mt * 32 + ks) * 2 + 0) * 64 + lane) * 8;
        size_t olo = ((((size_t)mt * 32 + ks) * 2 + 1) * 64 + lane) * 8;
        #pragma unroll
        for (int j = 0; j < 8; ++j) {
            int k = kbase + j;
            float wv = (k < Hdim) ? W_ih2[(size_t)(g * Hdim + u) * Hdim + k]
                                  : W_hh2[(size_t)(g * Hdim + u) * Hdim + (k - Hdim)];
            f16 hi = (f16)wv;
            f16 lo = (f16)(wv - (float)hi);
            aw2[ohi + j] = hi; aw2[olo + j] = lo;
        }
    }
    if (i < Hdim) {
        float4 bb1 = { b_ih1[i] + b_hh1[i],               b_ih1[Hdim+i] + b_hh1[Hdim+i],
                       b_ih1[2*Hdim+i] + b_hh1[2*Hdim+i], b_ih1[3*Hdim+i] + b_hh1[3*Hdim+i] };
        float4 bb2 = { b_ih2[i] + b_hh2[i],               b_ih2[Hdim+i] + b_hh2[Hdim+i],
                       b_ih2[2*Hdim+i] + b_hh2[2*Hdim+i], b_ih2[3*Hdim+i] + b_hh2[3*Hdim+i] };
        float4 wx  = { W_ih1[i], W_ih1[Hdim+i], W_ih1[2*Hdim+i], W_ih1[3*Hdim+i] };
        ((float4*)(ws + B1P_OFF))[i] = bb1;
        ((float4*)(ws + B2P_OFF))[i] = bb2;
        ((float4*)(ws + WX1_OFF))[i] = wx;
    }
    if (i < Tdim * Bdim) {
        int t = i >> 7, b = i & 127;
        ws[XT_OFF + i] = x[b * Tdim + t];
    }
    if (i < 262144) {                          // zero all 8 parities x 2 spl of h1,h2
        ((ull*)(ws + H1P_OFF))[i] = 0;
        ((ull*)(ws + H2P_OFF))[i] = 0;
    }
    if (i < 8192) ((unsigned*)(ws + ARR_OFF))[i] = 0u;
}

// ---------- persistent MFMA main kernel (two independent batch-groups) ----------
__global__ __launch_bounds__(256, 1) void lstm_main(float* ws,
                                                    const float* __restrict__ Wout,
                                                    const float* __restrict__ bout,
                                                    float* __restrict__ out) {
    const int tid  = threadIdx.x, bid = blockIdx.x;
    const int w    = tid >> 6;
    const int lane = tid & 63;
    const int quad = lane >> 4;
    const int col  = lane & 15;
    const bool is1  = (bid < NB1);
    const bool is2  = (bid >= NB1) && (bid < NB1 + NB2);
    const bool isout = (bid >= NB1 + NB2);

    __shared__ f16   awlds[65536];       // 128 KB weight A-fragments
    __shared__ float wout_lds[Hdim];
    __shared__ float psum[4][64];
    __shared__ float xflds[64];
    __shared__ float qpart[4][64];
    __shared__ ull   hstg[512];          // coalesced-store staging

    unsigned* flg = (unsigned*)(ws + ARR_OFF);
    unsigned short* stg = (unsigned short*)hstg;
    const float* xT = ws + XT_OFF;
    const float bout0 = bout[0];

    // ---- group + role geometry
    const int bid1 = is1 ? (bid & 31) : 0;              // G1 index within group
    const int gid  = is2 ? (bid - NB1) : 0;             // 0..127
    const int ug   = gid & 63;                          // G2 unit-group
    const int gA   = is1 ? (bid >> 5) : (is2 ? (gid >> 6) : (bid - NB1 - NB2)); // batch group
    const int ntw  = gA * 4 + w;                        // this wave's nt (16 cols)
    const int ks1  = bid1 >> 1, qp0 = (bid1 & 1) * 2;   // G1 store geometry
    const int ks2  = ug >> 2,  qg  = ug & 3;            // G2 store geometry

    // ---- waits (group-local flag sets; s_sleep(4) throttles poll traffic)
    auto wait3 = [&](unsigned T1, unsigned T2) {        // f1g(32) + f2g(64)
        if (tid < 64) {
            for (;;) {
                unsigned v1 = (lane < 32) ? cohloadu(flg + (gA*32 + lane) * FSTR) : 0xFFFFFFFFu;
                unsigned v2 = cohloadu(flg + (F2B + gA*64 + lane) * FSTR);
                if (__all(v1 >= T1 && v2 >= T2)) break;
                __builtin_amdgcn_s_sleep(4);
            }
        }
        asm volatile("" ::: "memory");
        __syncthreads();
    };
    auto wait1o = [&](unsigned T1, unsigned To) {       // f1g(32) + fog(1)
        if (tid < 64) {
            for (;;) {
                unsigned v1 = (lane < 32) ? cohloadu(flg + (gA*32 + lane) * FSTR)  : 0xFFFFFFFFu;
                unsigned vo = (lane == 0) ? cohloadu(flg + (FOB + gA) * FSTR)      : 0xFFFFFFFFu;
                if (__all(v1 >= T1 && vo >= To)) break;
                __builtin_amdgcn_s_sleep(4);
            }
        }
        asm volatile("" ::: "memory");
        __syncthreads();
    };
    auto wait2f = [&](unsigned T2) {                    // f2g(64) only
        if (tid < 64) {
            for (;;) {
                unsigned v2 = cohloadu(flg + (F2B + gA*64 + lane) * FSTR);
                if (__all(v2 >= T2)) break;
                __builtin_amdgcn_s_sleep(4);
            }
        }
        asm volatile("" ::: "memory");
        __syncthreads();
    };
    auto post = [&](unsigned* slot, unsigned val) {     // drain stores then own-line store
        __syncthreads();
        if (tid == 0)
            __hip_atomic_store(slot, val, __ATOMIC_RELAXED, __HIP_MEMORY_SCOPE_AGENT);
    };

    // fragment planes (8-deep ring)
    auto h1pf = [&](int par, int spl) {
        return (const half8*)((const unsigned short*)(ws + H1P_OFF) + (size_t)(par*2+spl) * 65536); };
    auto h2pf = [&](int par, int spl) {
        return (const half8*)((const unsigned short*)(ws + H2P_OFF) + (size_t)(par*2+spl) * 65536); };
    auto h1ull = [&](int par, int spl) {
        return (ull*)(ws + H1P_OFF) + (size_t)(par*2+spl) * 16384; };
    auto h2ull = [&](int par, int spl) {
        return (ull*)(ws + H2P_OFF) + (size_t)(par*2+spl) * 16384; };

    // ---- one-time: weight slice -> LDS
    if (is1) {
        half8* d = (half8*)awlds;
        const half8* s = (const half8*)(ws + AW1_OFF) + (size_t)bid1 * 8192;
        for (int i = tid; i < 8192; i += 256) d[i] = s[i];
    } else if (is2) {
        half8* d = (half8*)awlds;
        const half8* s = (const half8*)(ws + AW2_OFF) + (size_t)ug * 8192;
        for (int i = tid; i < 8192; i += 256) d[i] = s[i];
    }
    wout_lds[tid]       = Wout[tid];
    wout_lds[256 + tid] = Wout[256 + tid];
    __syncthreads();
    const half8* aw8 = (const half8*)awlds;

    const int bcol = ntw * 16 + col;                    // this lane's batch column
    int   u_[4];  float4 b1v[4], wxv[4];  float c1s[4];
    int   u2_[2]; float4 b2v[2];          float c2s[2];
    if (is1) {
        #pragma unroll
        for (int mt = 0; mt < 4; ++mt) {
            u_[mt]  = bid1 * 16 + mt * 4 + quad;
            b1v[mt] = ((const float4*)(ws + B1P_OFF))[u_[mt]];
            wxv[mt] = ((const float4*)(ws + WX1_OFF))[u_[mt]];
            c1s[mt] = 0.0f;
        }
    } else if (is2) {
        #pragma unroll
        for (int mt = 0; mt < 2; ++mt) {
            u2_[mt] = ug * 8 + mt * 4 + quad;
            b2v[mt] = ((const float4*)(ws + B2P_OFF))[u2_[mt]];
            c2s[mt] = 0.0f;
        }
    }

    // ---- G1 staging + coalesced publish (2 b64 stores/thread)
    auto stage1 = [&](int mt, float hv) {
        f16 hhi = (f16)hv;
        f16 hlo = (f16)(hv - (float)hhi);
        int mq = mt*4 + quad, qp = mq >> 3, jj = mq & 7;
        int hi = ((w*2 + qp)*16 + col)*8 + jj;          // per-spl stride 1024 halfs
        stg[hi]        = __builtin_bit_cast(unsigned short, hhi);
        stg[1024 + hi] = __builtin_bit_cast(unsigned short, hlo);
    };
    auto store1 = [&](int dpar) {
        __syncthreads();
        #pragma unroll
        for (int k = 0; k < 2; ++k) {
            int f = k * 256 + tid;                      // 0..511 flat b64
            int spl = f >> 8, r = f & 255;
            int ntl = r >> 6, rr = r & 63;
            int qp = rr >> 5, r2 = rr & 31, colp = r2 >> 1, pos = r2 & 1;
            cohstore64(h1ull(dpar, spl)
                       + (((gA*4 + ntl)*16 + ks1)*64 + (qp0 + qp)*16 + colp)*2 + pos,
                       hstg[f]);
        }
    };

    // ---- layer-1 step (1 nt/wave) ----
    auto gemm1 = [&](int spar, int dpar, float xv) {
        f32x4 acc[4] = {};
        const half8* fh = h1pf(spar, 0);
        const half8* fl = h1pf(spar, 1);
        half8 rh[8], rl[8];
        #pragma unroll
        for (int ks = 0; ks < 8; ++ks) {
            rh[ks] = fragload(fh + (ntw*16+ks)*64 + lane);
            rl[ks] = fragload(fl + (ntw*16+ks)*64 + lane);
        }
        #pragma unroll
        for (int ks = 0; ks < 16; ++ks) {
            half8 b0h = rh[ks&7], b0l = rl[ks&7];
            if (ks < 8) {
                int kp = ks + 8;
                rh[ks&7] = fragload(fh + (ntw*16+kp)*64 + lane);
                rl[ks&7] = fragload(fl + (ntw*16+kp)*64 + lane);
            }
            #pragma unroll
            for (int mt = 0; mt < 4; ++mt) {
                half8 ah = aw8[((mt*16 + ks)*2 + 0)*64 + lane];
                half8 al = aw8[((mt*16 + ks)*2 + 1)*64 + lane];
                acc[mt] = __builtin_amdgcn_mfma_f32_16x16x32_f16(ah, b0h, acc[mt], 0, 0, 0);
                acc[mt] = __builtin_amdgcn_mfma_f32_16x16x32_f16(al, b0h, acc[mt], 0, 0, 0);
                acc[mt] = __builtin_amdgcn_mfma_f32_16x16x32_f16(ah, b0l, acc[mt], 0, 0, 0);
            }
        }
        #pragma unroll
        for (int mt = 0; mt < 4; ++mt) {
            f32x4 g = acc[mt];
            float pi = g[0] + b1v[mt].x + wxv[mt].x * xv;
            float pf = g[1] + b1v[mt].y + wxv[mt].y * xv;
            float pg = g[2] + b1v[mt].z + wxv[mt].z * xv;
            float po = g[3] + b1v[mt].w + wxv[mt].w * xv;
            float c = fmaf(sigm(pf), c1s[mt], sigm(pi) * tanh_fast(pg));
            c1s[mt] = c;
            stage1(mt, sigm(po) * tanh_fast(c));
        }
        store1(dpar);
    };

    // ---- layer-2 step (1 nt/wave; group-local waits) ----
    auto g2_step = [&](int s) {
        int cpar = s & 7, ppar = (s - 1) & 7;
        const half8* fh = h1pf(cpar, 0);
        const half8* fl = h1pf(cpar, 1);
        const half8* gh = h2pf(ppar, 0);
        const half8* gl = h2pf(ppar, 1);

        wait1o((unsigned)(s + 1), (s >= RD) ? (unsigned)(s - (RD - 1)) : 0u);  // f1g + fog
        half8 rh[8], rl[8];
        #pragma unroll
        for (int ks = 0; ks < 8; ++ks) {            // prefetch h1-half first batch
            rh[ks] = fragload(fh + (ntw*16+ks)*64 + lane);
            rl[ks] = fragload(fl + (ntw*16+ks)*64 + lane);
        }
        wait2f((unsigned)s);                        // real wait: group h2(s-1) complete

        f32x4 acc[2] = {};
        #pragma unroll
        for (int ks = 0; ks < 32; ++ks) {
            half8 b0h = rh[ks&7], b0l = rl[ks&7];
            if (ks < 24) {
                int kp = ks + 8;
                const half8* sh = (kp < 16) ? fh : gh;
                const half8* sl = (kp < 16) ? fl : gl;
                int kq = (kp < 16) ? kp : kp - 16;
                rh[ks&7] = fragload(sh + (ntw*16+kq)*64 + lane);
                rl[ks&7] = fragload(sl + (ntw*16+kq)*64 + lane);
            }
            #pragma unroll
            for (int mt = 0; mt < 2; ++mt) {
                half8 ah = aw8[((mt*32 + ks)*2 + 0)*64 + lane];
                half8 al = aw8[((mt*32 + ks)*2 + 1)*64 + lane];
                acc[mt] = __builtin_amdgcn_mfma_f32_16x16x32_f16(ah, b0h, acc[mt], 0, 0, 0);
                acc[mt] = __builtin_amdgcn_mfma_f32_16x16x32_f16(al, b0h, acc[mt], 0, 0, 0);
                acc[mt] = __builtin_amdgcn_mfma_f32_16x16x32_f16(ah, b0l, acc[mt], 0, 0, 0);
            }
        }
        // epilogue: stage hi/lo then coalesced publish (1 b64 store/thread)
        #pragma unroll
        for (int mt = 0; mt < 2; ++mt) {
            f32x4 g = acc[mt];
            float pi = g[0] + b2v[mt].x;
            float pf = g[1] + b2v[mt].y;
            float pg = g[2] + b2v[mt].z;
            float po = g[3] + b2v[mt].w;
            float c = fmaf(sigm(pf), c2s[mt], sigm(pi) * tanh_fast(pg));
            c2s[mt] = c;
            float hv = sigm(po) * tanh_fast(c);
            f16 hhi = (f16)hv;
            f16 hlo = (f16)(hv - (float)hhi);
            int idx = ((w*16 + col)*8 + (mt*4 + quad));
            stg[idx]       = __builtin_bit_cast(unsigned short, hhi);
            stg[512 + idx] = __builtin_bit_cast(unsigned short, hlo);
        }
        __syncthreads();
        {
            int f = tid;                            // 0..255, 1 b64 each
            int spl = f >> 7, r = f & 127;
            int ntl = r >> 5, colp = (r >> 1) & 15, pos = r & 1;
            int nt = gA * 4 + ntl;
            cohstore64(h2ull(cpar, spl) + ((nt*16 + ks2)*64 + qg*16 + colp)*2 + pos, hstg[f]);
        }
        post(&flg[(F2B + gA*64 + ug) * FSTR], (unsigned)(s + 1));
    };

    // ================= GROUP 1 =================
    if (is1) {
        // prologue: h1(0) from x(0) (h1(-1)=0) -> parity 0
        #pragma unroll
        for (int mt = 0; mt < 4; ++mt) {
            float xv = xT[bcol];
            float pi = b1v[mt].x + wxv[mt].x * xv;
            float pg = b1v[mt].z + wxv[mt].z * xv;
            float po = b1v[mt].w + wxv[mt].w * xv;
            float c = sigm(pi) * tanh_fast(pg);
            c1s[mt] = c;
            stage1(mt, sigm(po) * tanh_fast(c));
        }
        store1(0);
        post(&flg[(gA*32 + bid1) * FSTR], 1u);

        // main: step t publishes h1(t+1); f1 -> t+2
        for (int t = 0; t <= Tdim - 2; ++t) {
            wait3((unsigned)(t + 1), (t >= RD - 1) ? (unsigned)(t - (RD - 2)) : 0u);
            gemm1(t & 7, (t + 1) & 7, xT[(t + 1) * Bdim + bcol]);
            post(&flg[(gA*32 + bid1) * FSTR], (unsigned)(t + 2));
        }

        // future: step t computes group-local feedback O(t-1), publishes h1(t)
        for (int t = Tdim; t < TT; ++t) {
            wait3((unsigned)t, (unsigned)t);
            {   // cooperative O(t-1) for this group's 64 cols
                int bl = tid & 63, kh = tid >> 6;        // kh 0..3 -> 4 ks each
                int nt = gA * 4 + (bl >> 4), nl = bl & 15;
                const half8* ph = h2pf((t - 1) & 7, 0);
                const half8* pl = h2pf((t - 1) & 7, 1);
                float a = 0.0f;
                #pragma unroll
                for (int kk = 0; kk < 4; ++kk) {
                    int ks = kh * 4 + kk;
                    #pragma unroll
                    for (int qd = 0; qd < 4; ++qd) {
                        half8 vh = fragload(ph + (nt*16+ks)*64 + qd*16 + nl);
                        half8 vl = fragload(pl + (nt*16+ks)*64 + qd*16 + nl);
                        int ub = ks*32 + qd*8;
                        #pragma unroll
                        for (int j = 0; j < 8; ++j)
                            a = fmaf((float)vh[j] + (float)vl[j], wout_lds[ub + j], a);
                    }
                }
                psum[kh][bl] = a;
                __syncthreads();
                if (tid < 64)
                    xflds[tid] = psum[0][tid] + psum[1][tid] + psum[2][tid]
                               + psum[3][tid] + bout0;
                __syncthreads();
                if (bid1 == 0 && tid < 64 && (t - 1) >= Tdim)
                    out[(size_t)(gA*64 + tid) * TT + (t - 1)] = xflds[tid];
            }
            gemm1((t - 1) & 7, t & 7, xflds[bcol & 63]);
            post(&flg[(gA*32 + bid1) * FSTR], (unsigned)(t + 1));
        }
    }
    // ================= GROUP 2 =================
    else if (is2) {
        for (int s = 0; s < TT; ++s) g2_step(s);
    }
    // ================= OUT blocks (one per group) =================
    else {
        int b = gA * 64 + lane;
        int nt = b >> 4, nl = b & 15;
        for (int s = 0; s < TT; ++s) {
            wait2f((unsigned)(s + 1));
            const half8* ph = h2pf(s & 7, 0);
            const half8* pl = h2pf(s & 7, 1);
            float a = 0.0f;
            #pragma unroll
            for (int kk = 0; kk < 4; ++kk) {
                int ks = w * 4 + kk;
                #pragma unroll
                for (int qd = 0; qd < 4; ++qd) {
                    half8 vh = fragload(ph + (nt*16+ks)*64 + qd*16 + nl);
                    half8 vl = fragload(pl + (nt*16+ks)*64 + qd*16 + nl);
                    int ub = ks*32 + qd*8;
                    #pragma unroll
                    for (int j = 0; j < 8; ++j)
                        a = fmaf((float)vh[j] + (float)vl[j], wout_lds[ub + j], a);
                }
            }
            qpart[w][lane] = a;
            __syncthreads();
            if (w == 0)
                out[(size_t)b * TT + s] = qpart[0][lane] + qpart[1][lane]
                                        + qpart[2][lane] + qpart[3][lane] + bout0;
            post(&flg[(FOB + gA) * FSTR], (unsigned)(s + 1));
        }
    }
}

extern "C" void kernel_launch(void* const* d_in, const int* in_sizes, int n_in,
                              void* d_out, int out_size, void* d_ws, size_t ws_size,
                              hipStream_t stream) {
    const float* x     = (const float*)d_in[0];
    const float* W_ih1 = (const float*)d_in[1];
    const float* W_hh1 = (const float*)d_in[2];
    const float* b_ih1 = (const float*)d_in[3];
    const float* b_hh1 = (const float*)d_in[4];
    const float* W_ih2 = (const float*)d_in[5];
    const float* W_hh2 = (const float*)d_in[6];
    const float* b_ih2 = (const float*)d_in[7];
    const float* b_hh2 = (const float*)d_in[8];
    const float* W_out = (const float*)d_in[9];
    const float* b_out = (const float*)d_in[10];
    float* ws  = (float*)d_ws;
    float* out = (float*)d_out;

    hipLaunchKernelGGL(lstm_prep, dim3(1536), dim3(256), 0, stream,
                       x, W_ih1, W_hh1, b_ih1, b_hh1, W_ih2, W_hh2, b_ih2, b_hh2, ws);
    hipLaunchKernelGGL(lstm_main, dim3(NBLK), dim3(256), 0, stream,
                       ws, W_out, b_out, out);
}